// Round 4
// baseline (2038.978 us; speedup 1.0000x reference)
//
#include <hip/hip_runtime.h>

typedef unsigned short ushort;
typedef unsigned int uint;
typedef __bf16 bf16x8 __attribute__((ext_vector_type(8)));
typedef float f32x4 __attribute__((ext_vector_type(4)));
typedef int i32x4 __attribute__((ext_vector_type(4)));

#define Bq 4096
#define Nq 17
#define DIMq 512
#define EPSq 1e-5f

__device__ inline ushort f2bf(float f) {
    unsigned u = __builtin_bit_cast(unsigned, f);
    u += 0x7fff + ((u >> 16) & 1);
    return (ushort)(u >> 16);
}
__device__ inline float bfs(ushort u) { return __builtin_bit_cast(float, (uint)u << 16); }
__device__ inline float bflo(uint u) { return __builtin_bit_cast(float, u << 16); }
__device__ inline float bfhi(uint u) { return __builtin_bit_cast(float, u & 0xffff0000u); }

__device__ inline f32x4 mfma16(bf16x8 a, bf16x8 b, f32x4 c) {
    return __builtin_amdgcn_mfma_f32_16x16x32_bf16(a, b, c, 0, 0, 0);
}

// ws: [0,289) A_sym | [512,1024) sum | [1024,1536) sumsq | [1536,2048) bn scale |
// [2048,2560) bn shift | byte 16384: wq bf16 1536x512 | byte 1589248: wp bf16 512x512

__global__ void k_prep(const float* __restrict__ adj, const float* __restrict__ adj2,
                       float* __restrict__ ws) {
    int t = threadIdx.x;
    if (t < Nq * Nq) {
        int n = t / Nq, m = t % Nq;
        ws[t] = 0.5f * ((adj[n * Nq + m] + adj2[n * Nq + m]) +
                        (adj[m * Nq + n] + adj2[m * Nq + n]));
    }
    ws[512 + t] = 0.f;
    ws[1024 + t] = 0.f;
}

__global__ __launch_bounds__(512) void k_stats(
    const float* __restrict__ x, const float* __restrict__ W,
    const float* __restrict__ Mg, const float* __restrict__ gbias,
    float* __restrict__ ws) {
    __shared__ float As[Nq * Nq];
    __shared__ float xs[2 * Nq];
    const int t = threadIdx.x;
    if (t < Nq * Nq) As[t] = ws[t];
    const float W00 = W[t], W01 = W[DIMq + t], W10 = W[2 * DIMq + t], W11 = W[3 * DIMq + t];
    const float gb = gbias[t];
    float Mr[Nq];
#pragma unroll
    for (int m = 0; m < Nq; m++) Mr[m] = Mg[m * DIMq + t];
    float sum = 0.f, sq = 0.f;
    for (int i = 0; i < 16; i++) {
        int b = blockIdx.x * 16 + i;
        __syncthreads();
        if (t < 2 * Nq) xs[t] = x[b * 2 * Nq + t];
        __syncthreads();
        float u[Nq];
#pragma unroll
        for (int m = 0; m < Nq; m++)
            u[m] = Mr[m] * (xs[2 * m] * W10 + xs[2 * m + 1] * W11);
#pragma unroll
        for (int n = 0; n < Nq; n++) {
            float S = gb;
#pragma unroll
            for (int m = 0; m < Nq; m++) S += As[n * Nq + m] * u[m];
            float dgn = Mr[n] * (xs[2 * n] * W00 + xs[2 * n + 1] * W01);
            float ov = S + As[n * Nq + n] * (dgn - u[n]);
            sum += ov;
            sq += ov * ov;
        }
    }
    atomicAdd(&ws[512 + t], sum);
    atomicAdd(&ws[1024 + t], sq);
}

__global__ void k_finalize(const float* __restrict__ bn_gamma,
                           const float* __restrict__ bn_beta,
                           float* __restrict__ ws) {
    int t = threadIdx.x;
    const float inv = 1.0f / (float)(Bq * Nq);
    float mean = ws[512 + t] * inv;
    float var = ws[1024 + t] * inv - mean * mean;
    float rstd = 1.0f / sqrtf(var + EPSq);
    float sc = bn_gamma[t] * rstd;
    ws[1536 + t] = sc;
    ws[2048 + t] = bn_beta[t] - mean * sc;
}

__global__ void k_wconv(const float* __restrict__ qkvw, const float* __restrict__ projw,
                        ushort* __restrict__ wq, ushort* __restrict__ wp) {
    int i = blockIdx.x * 256 + threadIdx.x;
    if (i < 1536 * 512) wq[i] = f2bf(qkvw[i]);
    if (i < 512 * 512) wp[i] = f2bf(projw[i]);
}

// LDS (bytes): 0 xn[17][512]bf16 swz | 17408 q/o | 34816 k | 52224 v |
// 69632 P per-wave [8][640]; pAcc f32[17][512] aliases k+v after attention.
__global__ __launch_bounds__(512, 4) void k_fused(
    const float* __restrict__ x, const float* __restrict__ W,
    const float* __restrict__ Mg, const float* __restrict__ gbias,
    const float* __restrict__ pos, const float* __restrict__ lng,
    const float* __restrict__ lnb, const float* __restrict__ projb,
    const float* __restrict__ ws, const ushort* __restrict__ wq,
    const ushort* __restrict__ wp, float* __restrict__ out) {
    __shared__ __align__(16) char S[74752];
    char* xnC = S;
    char* qoC = S + 17408;
    char* kC = S + 34816;
    char* vC = S + 52224;
    char* pC = S + 69632;
    // phase-1 scratch aliases kC (dead until phase 2 writes k)
    float* As = (float*)kC;          // 289
    float* xs = As + 289;            // 34
    float* red = xs + 34;            // 272
    float* stats = red + 272;        // 34
    float* muv = stats + 34;         // 17
    float* rsv = muv + 17;           // 17

    const int t = threadIdx.x;
    const int b = blockIdx.x;
    const int lane = t & 63, w = t >> 6;
    const int l15 = lane & 15, g = lane >> 4;
    const int aswz0 = (l15 & 7) << 4;

    // zero this wave's P buffer (pad col 17 must stay 0)
    for (int i = lane; i < 40; i += 64)
        ((i32x4*)(pC + w * 640))[i] = (i32x4){0, 0, 0, 0};

    if (t < 289) As[t] = ws[t];
    if (t < 34) xs[t] = x[b * 34 + t];

    const float W00 = W[t], W01 = W[512 + t], W10 = W[1024 + t], W11 = W[1536 + t];
    const float gb = gbias[t];
    const float bsc = ws[1536 + t], bsh = ws[2048 + t];
    const float lg = lng[t], lb = lnb[t], pb = projb[t];
    __syncthreads();  // (1)

    // ---- phase 1: graph conv + BN + relu + pos (residual xp in regs) ----
    float xp[17];
    {
        float u_[17], dg_[17];
#pragma unroll
        for (int m = 0; m < 17; m++) {
            float Mv = Mg[m * 512 + t];
            float x0 = xs[2 * m], x1 = xs[2 * m + 1];
            u_[m] = Mv * (x0 * W10 + x1 * W11);
            dg_[m] = Mv * (x0 * W00 + x1 * W01);
        }
#pragma unroll
        for (int n = 0; n < 17; n++) {
            float Sv = gb;
#pragma unroll
            for (int m = 0; m < 17; m++) Sv += As[n * 17 + m] * u_[m];
            float ov = Sv + As[n * 17 + n] * (dg_[n] - u_[n]);
            xp[n] = fmaxf(ov * bsc + bsh, 0.f) + pos[n * 512 + t];
        }
    }
    // ---- LayerNorm stats ----
#pragma unroll
    for (int n = 0; n < 17; n++) {
        float a = xp[n], q2 = xp[n] * xp[n];
#pragma unroll
        for (int off = 32; off; off >>= 1) {
            a += __shfl_xor(a, off);
            q2 += __shfl_xor(q2, off);
        }
        if (lane == 0) { red[w * 34 + n] = a; red[w * 34 + 17 + n] = q2; }
    }
    __syncthreads();  // (2)
    if (t < 34) {
        float s = 0.f;
#pragma unroll
        for (int ww = 0; ww < 8; ww++) s += red[ww * 34 + t];
        stats[t] = s;
    }
    __syncthreads();  // (3)
    if (t < 17) {
        float mu = stats[t] * (1.f / 512.f);
        float var = stats[17 + t] * (1.f / 512.f) - mu * mu;
        muv[t] = mu;
        rsv[t] = 1.f / sqrtf(var + EPSq);
    }
    __syncthreads();  // (4)
    {
        ushort* xnU = (ushort*)xnC;
#pragma unroll
        for (int n = 0; n < 17; n++) {
            int sw = (n & 7) << 4;
            float xnv = (xp[n] - muv[n]) * rsv[n] * lg + lb;
            xnU[(n * 1024 + ((2 * t) ^ sw)) >> 1] = f2bf(xnv);
        }
    }
    __syncthreads();  // (5) xn ready; phase-1 scratch dead

    // ---- phase 2: qkv GEMM; wave w owns N-tiles [12w, 12w+12) of 96 ----
    {
        const char* a0b = xnC + l15 * 1024;
        const char* a1b = xnC + 16 * 1024;
#pragma unroll 1
        for (int c = 0; c < 2; c++) {
            int tbase = w * 12 + c * 6;
            f32x4 acc0[6], acc1[6];
#pragma unroll
            for (int j = 0; j < 6; j++) {
                acc0[j] = (f32x4){0.f, 0.f, 0.f, 0.f};
                acc1[j] = (f32x4){0.f, 0.f, 0.f, 0.f};
            }
            const ushort* bp[6];
#pragma unroll
            for (int j = 0; j < 6; j++)
                bp[j] = wq + (size_t)((tbase + j) * 16 + l15) * 512 + g * 8;
#pragma unroll 4
            for (int ks = 0; ks < 16; ks++) {
                int colb = ks * 64 + g * 16;
                bf16x8 a0 = *(const bf16x8*)(a0b + (colb ^ aswz0));
                bf16x8 a1 = *(const bf16x8*)(a1b + colb);
#pragma unroll
                for (int j = 0; j < 6; j++) {
                    bf16x8 bv = *(const bf16x8*)(bp[j] + ks * 32);
                    acc0[j] = mfma16(a0, bv, acc0[j]);
                    acc1[j] = mfma16(a1, bv, acc1[j]);
                }
            }
#pragma unroll
            for (int j = 0; j < 6; j++) {
                int t_ = tbase + j;
                int which = t_ >> 5;
                int col = (t_ & 31) * 16 + l15;
                char* dst = which == 0 ? qoC : (which == 1 ? kC : vC);
#pragma unroll
                for (int r = 0; r < 4; r++) {
                    int n = g * 4 + r;
                    *(ushort*)(dst + n * 1024 + ((2 * col) ^ ((n & 7) << 4))) = f2bf(acc0[j][r]);
                }
                if (g == 0)
                    *(ushort*)(dst + 16 * 1024 + 2 * col) = f2bf(acc1[j][0]);
            }
        }
    }
    __syncthreads();  // (6) q,k,v ready

    // ---- phase 3a: scores + softmax, head w per wave ----
    ushort* pw16 = (ushort*)(pC + w * 640);
    {
        const int hb = w * 128;
        f32x4 sa[2][2];
        sa[0][0] = (f32x4){0.f, 0.f, 0.f, 0.f}; sa[0][1] = sa[0][0];
        sa[1][0] = sa[0][0]; sa[1][1] = sa[0][0];
#pragma unroll
        for (int ks2 = 0; ks2 < 2; ks2++) {
            int cb = hb + ks2 * 64 + g * 16;
            bf16x8 qa0 = *(const bf16x8*)(qoC + l15 * 1024 + (cb ^ aswz0));
            bf16x8 qa1 = *(const bf16x8*)(qoC + 16 * 1024 + cb);
            bf16x8 kb0 = *(const bf16x8*)(kC + l15 * 1024 + (cb ^ aswz0));
            bf16x8 kb1 = *(const bf16x8*)(kC + 16 * 1024 + cb);
            sa[0][0] = mfma16(qa0, kb0, sa[0][0]);
            sa[1][0] = mfma16(qa1, kb0, sa[1][0]);
            sa[0][1] = mfma16(qa0, kb1, sa[0][1]);
            sa[1][1] = mfma16(qa1, kb1, sa[1][1]);
        }
#pragma unroll
        for (int mt = 0; mt < 2; mt++)
#pragma unroll
            for (int r = 0; r < 4; r++) {
                float sc0 = sa[mt][0][r] * 0.125f;
                float sc1v = sa[mt][1][r] * 0.125f;
                float sc1 = (l15 == 0) ? sc1v : -1e30f;
                float mx = fmaxf(sc0, sc1);
#pragma unroll
                for (int off = 1; off < 16; off <<= 1) mx = fmaxf(mx, __shfl_xor(mx, off));
                float e0 = __expf(sc0 - mx);
                float e1 = (l15 == 0) ? __expf(sc1v - mx) : 0.f;
                float sm = e0 + e1;
#pragma unroll
                for (int off = 1; off < 16; off <<= 1) sm += __shfl_xor(sm, off);
                float ri = 1.f / sm;
                int n = mt * 16 + g * 4 + r;
                if (n < 17) {
                    pw16[n * 18 + l15] = f2bf(e0 * ri);
                    if (l15 == 0) pw16[n * 18 + 16] = f2bf(e1 * ri);
                }
            }
    }
    __syncthreads();  // (7) q reads done; o may overwrite q

    // ---- phase 3b: PV in VALU, head w per wave; write o over q region ----
    {
        const int hb = w * 128;
        float vv[18];
        vv[17] = 0.f;
#pragma unroll
        for (int m = 0; m < 17; m++)
            vv[m] = bfs(*(const ushort*)(vC + m * 1024 + ((hb + 2 * lane) ^ ((m & 7) << 4))));
        const uint* pr = (const uint*)(pC + w * 640);
#pragma unroll
        for (int n = 0; n < 17; n++) {
            float o_ = 0.f;
#pragma unroll
            for (int q = 0; q < 9; q++) {
                uint p2 = pr[n * 9 + q];
                o_ += bflo(p2) * vv[2 * q] + bfhi(p2) * vv[2 * q + 1];
            }
            *(ushort*)(qoC + n * 1024 + ((hb + 2 * lane) ^ ((n & 7) << 4))) = f2bf(o_);
        }
    }
    __syncthreads();  // (8) o complete

    // ---- phase 4: proj GEMM; wave w owns out cols [64w, 64w+64) ----
    float* pAcc = (float*)kC;  // [17][512], aliases k+v (dead)
    {
        f32x4 pa0[4], pa1[4];
#pragma unroll
        for (int nt = 0; nt < 4; nt++) {
            pa0[nt] = (f32x4){0.f, 0.f, 0.f, 0.f};
            pa1[nt] = (f32x4){0.f, 0.f, 0.f, 0.f};
        }
        const ushort* wpB[4];
#pragma unroll
        for (int nt = 0; nt < 4; nt++)
            wpB[nt] = wp + (size_t)(w * 64 + nt * 16 + l15) * 512 + g * 8;
#pragma unroll 4
        for (int ks = 0; ks < 16; ks++) {
            int colb = ks * 64 + g * 16;
            bf16x8 a0 = *(const bf16x8*)(qoC + l15 * 1024 + (colb ^ aswz0));
            bf16x8 a1 = *(const bf16x8*)(qoC + 16 * 1024 + colb);
#pragma unroll
            for (int nt = 0; nt < 4; nt++) {
                bf16x8 bv = *(const bf16x8*)(wpB[nt] + ks * 32);
                pa0[nt] = mfma16(a0, bv, pa0[nt]);
                pa1[nt] = mfma16(a1, bv, pa1[nt]);
            }
        }
#pragma unroll
        for (int nt = 0; nt < 4; nt++) {
            int col = w * 64 + nt * 16 + l15;
#pragma unroll
            for (int r = 0; r < 4; r++) {
                int n = g * 4 + r;
                pAcc[n * 512 + col] = pa0[nt][r];
            }
            if (g == 0) pAcc[16 * 512 + col] = pa1[nt][0];
        }
    }
    __syncthreads();  // (9)
#pragma unroll
    for (int n = 0; n < 17; n++) {
        size_t o0 = ((size_t)b * 17 + n) * 512;
        out[o0 + t] = xp[n] + pAcc[n * 512 + t] + pb;
    }
}

extern "C" void kernel_launch(void* const* d_in, const int* in_sizes, int n_in,
                              void* d_out, int out_size, void* d_ws, size_t ws_size,
                              hipStream_t stream) {
    const float* x = (const float*)d_in[0];
    const float* adj = (const float*)d_in[1];
    const float* adj2 = (const float*)d_in[2];
    const float* W = (const float*)d_in[3];
    const float* Mg = (const float*)d_in[4];
    const float* gbias = (const float*)d_in[5];
    const float* bng = (const float*)d_in[6];
    const float* bnb = (const float*)d_in[7];
    const float* pos = (const float*)d_in[8];
    const float* lng = (const float*)d_in[9];
    const float* lnb = (const float*)d_in[10];
    const float* qkvw = (const float*)d_in[11];
    const float* projw = (const float*)d_in[12];
    const float* projb = (const float*)d_in[13];
    float* ws = (float*)d_ws;
    float* out = (float*)d_out;
    ushort* wq = (ushort*)((char*)d_ws + 16384);
    ushort* wp = (ushort*)((char*)d_ws + 16384 + 1536 * 512 * 2);

    k_prep<<<1, 512, 0, stream>>>(adj, adj2, ws);
    k_stats<<<256, 512, 0, stream>>>(x, W, Mg, gbias, ws);
    k_finalize<<<1, 512, 0, stream>>>(bng, bnb, ws);
    k_wconv<<<3072, 256, 0, stream>>>(qkvw, projw, wq, wp);
    k_fused<<<Bq, 512, 0, stream>>>(x, W, Mg, gbias, pos, lng, lnb, projb,
                                    ws, wq, wp, out);
}

// Round 5
// 670.412 us; speedup vs baseline: 3.0414x; 3.0414x over previous
//
#include <hip/hip_runtime.h>

typedef unsigned short ushort;
typedef unsigned int uint;
typedef __bf16 bf16x8 __attribute__((ext_vector_type(8)));
typedef float f32x4 __attribute__((ext_vector_type(4)));
typedef int i32x4 __attribute__((ext_vector_type(4)));

#define Bq 4096
#define Nq 17
#define DIMq 512
#define EPSq 1e-5f

__device__ inline ushort f2bf(float f) {
    unsigned u = __builtin_bit_cast(unsigned, f);
    u += 0x7fff + ((u >> 16) & 1);
    return (ushort)(u >> 16);
}
__device__ inline float bfs(ushort u) { return __builtin_bit_cast(float, (uint)u << 16); }
__device__ inline float bflo(uint u) { return __builtin_bit_cast(float, u << 16); }
__device__ inline float bfhi(uint u) { return __builtin_bit_cast(float, u & 0xffff0000u); }

__device__ inline f32x4 mfma16(bf16x8 a, bf16x8 b, f32x4 c) {
    return __builtin_amdgcn_mfma_f32_16x16x32_bf16(a, b, c, 0, 0, 0);
}

// async global->LDS, 16B per lane; lds dest = wave-uniform base + lane*16
__device__ inline void gl16(const ushort* g, ushort* l) {
    __builtin_amdgcn_global_load_lds(
        (const __attribute__((address_space(1))) unsigned int*)g,
        (__attribute__((address_space(3))) unsigned int*)l, 16, 0, 0);
}

// ws bytes: [0) misc floats (A_sym 289 | 512:sum | 1024:sumsq | 1536:bnscale | 2048:bnshift)
// 16384: wq bf16 [1536][512] (q-rows pre-scaled by 0.125)
// 1589248: wp bf16 [512][512]
// 2113536: xn bf16 [69632][512]  (later reused as o bf16, same rows)
// 73416704: qkv bf16 [rows_per_pass][1536]

__global__ void k_prep(const float* __restrict__ adj, const float* __restrict__ adj2,
                       float* __restrict__ ws) {
    int t = threadIdx.x;
    if (t < Nq * Nq) {
        int n = t / Nq, m = t % Nq;
        ws[t] = 0.5f * ((adj[n * Nq + m] + adj2[n * Nq + m]) +
                        (adj[m * Nq + n] + adj2[m * Nq + n]));
    }
    ws[512 + t] = 0.f;
    ws[1024 + t] = 0.f;
}

__global__ __launch_bounds__(512) void k_stats(
    const float* __restrict__ x, const float* __restrict__ W,
    const float* __restrict__ Mg, const float* __restrict__ gbias,
    float* __restrict__ ws) {
    __shared__ float As[Nq * Nq];
    __shared__ float xs[2 * Nq];
    const int t = threadIdx.x;
    if (t < Nq * Nq) As[t] = ws[t];
    const float W00 = W[t], W01 = W[DIMq + t], W10 = W[2 * DIMq + t], W11 = W[3 * DIMq + t];
    const float gb = gbias[t];
    float Mr[Nq];
#pragma unroll
    for (int m = 0; m < Nq; m++) Mr[m] = Mg[m * DIMq + t];
    float sum = 0.f, sq = 0.f;
    for (int i = 0; i < 16; i++) {
        int b = blockIdx.x * 16 + i;
        __syncthreads();
        if (t < 2 * Nq) xs[t] = x[b * 2 * Nq + t];
        __syncthreads();
        float u[Nq];
#pragma unroll
        for (int m = 0; m < Nq; m++)
            u[m] = Mr[m] * (xs[2 * m] * W10 + xs[2 * m + 1] * W11);
#pragma unroll
        for (int n = 0; n < Nq; n++) {
            float S = gb;
#pragma unroll
            for (int m = 0; m < Nq; m++) S += As[n * Nq + m] * u[m];
            float dgn = Mr[n] * (xs[2 * n] * W00 + xs[2 * n + 1] * W01);
            float ov = S + As[n * Nq + n] * (dgn - u[n]);
            sum += ov;
            sq += ov * ov;
        }
    }
    atomicAdd(&ws[512 + t], sum);
    atomicAdd(&ws[1024 + t], sq);
}

__global__ void k_finalize(const float* __restrict__ bn_gamma,
                           const float* __restrict__ bn_beta,
                           float* __restrict__ ws) {
    int t = threadIdx.x;
    const float inv = 1.0f / (float)(Bq * Nq);
    float mean = ws[512 + t] * inv;
    float var = ws[1024 + t] * inv - mean * mean;
    float rstd = 1.0f / sqrtf(var + EPSq);
    float sc = bn_gamma[t] * rstd;
    ws[1536 + t] = sc;
    ws[2048 + t] = bn_beta[t] - mean * sc;
}

// weights -> bf16; q-rows (d<512) of wq folded with the 1/8 attention scale
__global__ void k_wconv(const float* __restrict__ qkvw, const float* __restrict__ projw,
                        ushort* __restrict__ wq, ushort* __restrict__ wp) {
    int i = blockIdx.x * 256 + threadIdx.x;
    if (i < 1536 * 512) {
        float v = qkvw[i];
        if ((i >> 9) < 512) v *= 0.125f;
        wq[i] = f2bf(v);
    }
    if (i < 512 * 512) wp[i] = f2bf(projw[i]);
}

// ---- phase 1 kernel: graphconv+BN+relu+pos+LN; xn bf16 -> ws, xp f32 -> out ----
__global__ __launch_bounds__(256) void k_pre(
    const float* __restrict__ x, const float* __restrict__ W,
    const float* __restrict__ Mg, const float* __restrict__ gbias,
    const float* __restrict__ pos, const float* __restrict__ lng,
    const float* __restrict__ lnb, const float* __restrict__ ws,
    ushort* __restrict__ xn, float* __restrict__ outp) {
    __shared__ float As[289], xs[34], red[136], stats[34], muv[17], rsv[17];
    const int t = threadIdx.x, b = blockIdx.x;
    const int lane = t & 63, w = t >> 6;
    for (int i = t; i < 289; i += 256) As[i] = ws[i];
    if (t < 34) xs[t] = x[b * 34 + t];
    float W00[2], W01[2], W10[2], W11[2], gb2[2], bsc[2], bsh[2], lg[2], lb[2];
#pragma unroll
    for (int j = 0; j < 2; j++) {
        int c = t + j * 256;
        W00[j] = W[c]; W01[j] = W[512 + c]; W10[j] = W[1024 + c]; W11[j] = W[1536 + c];
        gb2[j] = gbias[c]; bsc[j] = ws[1536 + c]; bsh[j] = ws[2048 + c];
        lg[j] = lng[c]; lb[j] = lnb[c];
    }
    __syncthreads();
    float xp[17][2];
    {
        float u_[17][2], dg_[17][2];
#pragma unroll
        for (int m = 0; m < 17; m++) {
            float x0 = xs[2 * m], x1 = xs[2 * m + 1];
#pragma unroll
            for (int j = 0; j < 2; j++) {
                float Mv = Mg[m * 512 + t + j * 256];
                u_[m][j] = Mv * (x0 * W10[j] + x1 * W11[j]);
                dg_[m][j] = Mv * (x0 * W00[j] + x1 * W01[j]);
            }
        }
#pragma unroll
        for (int n = 0; n < 17; n++) {
            float S0 = gb2[0], S1 = gb2[1];
#pragma unroll
            for (int m = 0; m < 17; m++) {
                float a = As[n * 17 + m];
                S0 += a * u_[m][0];
                S1 += a * u_[m][1];
            }
            float ad = As[n * 17 + n];
            float ov0 = S0 + ad * (dg_[n][0] - u_[n][0]);
            float ov1 = S1 + ad * (dg_[n][1] - u_[n][1]);
            xp[n][0] = fmaxf(ov0 * bsc[0] + bsh[0], 0.f) + pos[n * 512 + t];
            xp[n][1] = fmaxf(ov1 * bsc[1] + bsh[1], 0.f) + pos[n * 512 + t + 256];
        }
    }
#pragma unroll
    for (int n = 0; n < 17; n++) {
        float a = xp[n][0] + xp[n][1];
        float q2 = xp[n][0] * xp[n][0] + xp[n][1] * xp[n][1];
#pragma unroll
        for (int off = 32; off; off >>= 1) {
            a += __shfl_xor(a, off);
            q2 += __shfl_xor(q2, off);
        }
        if (lane == 0) { red[w * 34 + n] = a; red[w * 34 + 17 + n] = q2; }
    }
    __syncthreads();
    if (t < 34) stats[t] = red[t] + red[34 + t] + red[68 + t] + red[102 + t];
    __syncthreads();
    if (t < 17) {
        float mu = stats[t] * (1.f / 512.f);
        float var = stats[17 + t] * (1.f / 512.f) - mu * mu;
        muv[t] = mu;
        rsv[t] = 1.f / sqrtf(var + EPSq);
    }
    __syncthreads();
#pragma unroll
    for (int n = 0; n < 17; n++) {
        size_t rb = (size_t)(b * 17 + n) * 512;
#pragma unroll
        for (int j = 0; j < 2; j++) {
            int c = t + j * 256;
            float xnv = (xp[n][j] - muv[n]) * rsv[n] * lg[j] + lb[j];
            xn[rb + c] = f2bf(xnv);
            outp[rb + c] = xp[n][j];
        }
    }
}

// ---- 128x128xBK32 GEMM (C = A * B^T), bf16 out: qkv = xn x wq^T ----
__global__ __launch_bounds__(256, 2) void k_qkv(
    const ushort* __restrict__ A, const ushort* __restrict__ Bw,
    ushort* __restrict__ C) {
    __shared__ __align__(16) ushort At[128 * 32];
    __shared__ __align__(16) ushort Bt[128 * 32];
    const int t = threadIdx.x, lane = t & 63, w = t >> 6;
    const int l15 = lane & 15, g = lane >> 4;
    const int wm = w >> 1, wn = w & 1;
    const int tmr = blockIdx.x * 128, tnr = blockIdx.y * 128;
    const int srow = lane >> 2, sseg = lane & 3;
    const int seglog = sseg ^ ((srow >> 1) & 3);  // source-side swizzle
    f32x4 acc[4][4];
#pragma unroll
    for (int i = 0; i < 4; i++)
#pragma unroll
        for (int j = 0; j < 4; j++) acc[i][j] = (f32x4){0.f, 0.f, 0.f, 0.f};
    const size_t aB0 = (size_t)(tmr + w * 16 + srow) * 512 + seglog * 8;
    const size_t aB1 = aB0 + (size_t)64 * 512;
    const size_t bB0 = (size_t)(tnr + w * 16 + srow) * 512 + seglog * 8;
    const size_t bB1 = bB0 + (size_t)64 * 512;
    ushort* AtW0 = &At[(w * 16) * 32];
    ushort* AtW1 = &At[(64 + w * 16) * 32];
    ushort* BtW0 = &Bt[(w * 16) * 32];
    ushort* BtW1 = &Bt[(64 + w * 16) * 32];
    for (int kt = 0; kt < 16; kt++) {
        __syncthreads();
        int ko = kt * 32;
        gl16(A + aB0 + ko, AtW0);
        gl16(A + aB1 + ko, AtW1);
        gl16(Bw + bB0 + ko, BtW0);
        gl16(Bw + bB1 + ko, BtW1);
        __syncthreads();
        bf16x8 af[4], bf_[4];
#pragma unroll
        for (int mt = 0; mt < 4; mt++) {
            int row = wm * 64 + mt * 16 + l15;
            af[mt] = *(const bf16x8*)&At[row * 32 + (g ^ ((row >> 1) & 3)) * 8];
        }
#pragma unroll
        for (int nt = 0; nt < 4; nt++) {
            int row = wn * 64 + nt * 16 + l15;
            bf_[nt] = *(const bf16x8*)&Bt[row * 32 + (g ^ ((row >> 1) & 3)) * 8];
        }
#pragma unroll
        for (int mt = 0; mt < 4; mt++)
#pragma unroll
            for (int nt = 0; nt < 4; nt++)
                acc[mt][nt] = mfma16(af[mt], bf_[nt], acc[mt][nt]);
    }
#pragma unroll
    for (int mt = 0; mt < 4; mt++) {
        int grow = tmr + wm * 64 + mt * 16 + g * 4;
#pragma unroll
        for (int nt = 0; nt < 4; nt++) {
            int gcol = tnr + wn * 64 + nt * 16 + l15;
#pragma unroll
            for (int r = 0; r < 4; r++)
                C[(size_t)(grow + r) * 1536 + gcol] = f2bf(acc[mt][nt][r]);
        }
    }
}

// ---- attention: 1 wave = 1 (sample, head) ----
__global__ __launch_bounds__(256, 4) void k_attn(
    const ushort* __restrict__ qkv, ushort* __restrict__ o, int s0) {
    __shared__ __align__(16) char pC[4 * 640];
    const int t = threadIdx.x, lane = t & 63, w = t >> 6;
    const int l15 = lane & 15, g = lane >> 4;
    const int hl = blockIdx.x * 4 + w;
    const int sl = hl >> 3, h = hl & 7;
    const size_t rb = (size_t)sl * 17;
    for (int i = lane; i < 40; i += 64)
        ((i32x4*)(pC + w * 640))[i] = (i32x4){0, 0, 0, 0};
    // scores (wq q-rows pre-scaled, so no 0.125 here)
    const ushort* qb = qkv + rb * 1536 + h * 64;
    const ushort* kb = qkv + rb * 1536 + 512 + h * 64;
    f32x4 sa[2][2];
    sa[0][0] = (f32x4){0.f, 0.f, 0.f, 0.f}; sa[0][1] = sa[0][0];
    sa[1][0] = sa[0][0]; sa[1][1] = sa[0][0];
#pragma unroll
    for (int ks2 = 0; ks2 < 2; ks2++) {
        int co = ks2 * 32 + g * 8;
        bf16x8 qa0 = *(const bf16x8*)(qb + (size_t)l15 * 1536 + co);
        bf16x8 qa1 = *(const bf16x8*)(qb + (size_t)16 * 1536 + co);
        bf16x8 kb0 = *(const bf16x8*)(kb + (size_t)l15 * 1536 + co);
        bf16x8 kb1 = *(const bf16x8*)(kb + (size_t)16 * 1536 + co);
        sa[0][0] = mfma16(qa0, kb0, sa[0][0]);
        sa[1][0] = mfma16(qa1, kb0, sa[1][0]);
        sa[0][1] = mfma16(qa0, kb1, sa[0][1]);
        sa[1][1] = mfma16(qa1, kb1, sa[1][1]);
    }
    ushort* pw16 = (ushort*)(pC + w * 640);
#pragma unroll
    for (int mt = 0; mt < 2; mt++)
#pragma unroll
        for (int r = 0; r < 4; r++) {
            float sc0 = sa[mt][0][r];
            float sc1v = sa[mt][1][r];
            float sc1 = (l15 == 0) ? sc1v : -1e30f;
            float mx = fmaxf(sc0, sc1);
#pragma unroll
            for (int off = 1; off < 16; off <<= 1) mx = fmaxf(mx, __shfl_xor(mx, off));
            float e0 = __expf(sc0 - mx);
            float e1 = (l15 == 0) ? __expf(sc1v - mx) : 0.f;
            float sm = e0 + e1;
#pragma unroll
            for (int off = 1; off < 16; off <<= 1) sm += __shfl_xor(sm, off);
            float ri = 1.f / sm;
            int n = mt * 16 + g * 4 + r;
            if (n < 17) {
                pw16[n * 18 + l15] = f2bf(e0 * ri);
                if (l15 == 0) pw16[n * 18 + 16] = f2bf(e1 * ri);
            }
        }
    __syncthreads();
    // PV: lane owns one head-column
    const ushort* vb = qkv + rb * 1536 + 1024 + h * 64;
    float vv[18];
    vv[17] = 0.f;
#pragma unroll
    for (int m = 0; m < 17; m++) vv[m] = bfs(vb[(size_t)m * 1536 + lane]);
    const uint* pr = (const uint*)(pC + w * 640);
    const size_t ob = (size_t)(s0 + sl) * 17;
#pragma unroll
    for (int n = 0; n < 17; n++) {
        float o_ = 0.f;
#pragma unroll
        for (int q = 0; q < 9; q++) {
            uint p2 = pr[n * 9 + q];
            o_ += bflo(p2) * vv[2 * q] + bfhi(p2) * vv[2 * q + 1];
        }
        o[(ob + n) * 512 + h * 64 + lane] = f2bf(o_);
    }
}

// ---- proj GEMM + residual + bias: out = o x wp^T + out(=xp) + pb ----
__global__ __launch_bounds__(256, 2) void k_proj(
    const ushort* __restrict__ A, const ushort* __restrict__ Bw,
    const float* __restrict__ projb, float* __restrict__ outp) {
    __shared__ __align__(16) ushort At[128 * 32];
    __shared__ __align__(16) ushort Bt[128 * 32];
    const int t = threadIdx.x, lane = t & 63, w = t >> 6;
    const int l15 = lane & 15, g = lane >> 4;
    const int wm = w >> 1, wn = w & 1;
    const int tmr = blockIdx.x * 128, tnr = blockIdx.y * 128;
    const int srow = lane >> 2, sseg = lane & 3;
    const int seglog = sseg ^ ((srow >> 1) & 3);
    f32x4 acc[4][4];
#pragma unroll
    for (int i = 0; i < 4; i++)
#pragma unroll
        for (int j = 0; j < 4; j++) acc[i][j] = (f32x4){0.f, 0.f, 0.f, 0.f};
    const size_t aB0 = (size_t)(tmr + w * 16 + srow) * 512 + seglog * 8;
    const size_t aB1 = aB0 + (size_t)64 * 512;
    const size_t bB0 = (size_t)(tnr + w * 16 + srow) * 512 + seglog * 8;
    const size_t bB1 = bB0 + (size_t)64 * 512;
    ushort* AtW0 = &At[(w * 16) * 32];
    ushort* AtW1 = &At[(64 + w * 16) * 32];
    ushort* BtW0 = &Bt[(w * 16) * 32];
    ushort* BtW1 = &Bt[(64 + w * 16) * 32];
    for (int kt = 0; kt < 16; kt++) {
        __syncthreads();
        int ko = kt * 32;
        gl16(A + aB0 + ko, AtW0);
        gl16(A + aB1 + ko, AtW1);
        gl16(Bw + bB0 + ko, BtW0);
        gl16(Bw + bB1 + ko, BtW1);
        __syncthreads();
        bf16x8 af[4], bf_[4];
#pragma unroll
        for (int mt = 0; mt < 4; mt++) {
            int row = wm * 64 + mt * 16 + l15;
            af[mt] = *(const bf16x8*)&At[row * 32 + (g ^ ((row >> 1) & 3)) * 8];
        }
#pragma unroll
        for (int nt = 0; nt < 4; nt++) {
            int row = wn * 64 + nt * 16 + l15;
            bf_[nt] = *(const bf16x8*)&Bt[row * 32 + (g ^ ((row >> 1) & 3)) * 8];
        }
#pragma unroll
        for (int mt = 0; mt < 4; mt++)
#pragma unroll
            for (int nt = 0; nt < 4; nt++)
                acc[mt][nt] = mfma16(af[mt], bf_[nt], acc[mt][nt]);
    }
#pragma unroll
    for (int mt = 0; mt < 4; mt++) {
        int grow = tmr + wm * 64 + mt * 16 + g * 4;
#pragma unroll
        for (int nt = 0; nt < 4; nt++) {
            int gcol = tnr + wn * 64 + nt * 16 + l15;
            float pbv = projb[gcol];
#pragma unroll
            for (int r = 0; r < 4; r++) {
                size_t idx = (size_t)(grow + r) * 512 + gcol;
                outp[idx] = acc[mt][nt][r] + outp[idx] + pbv;
            }
        }
    }
}

// ---- fallback: round-3 fused kernel (wq q-rows pre-scaled -> no 0.125) ----
__global__ __launch_bounds__(256, 2) void k_fused(
    const float* __restrict__ x, const float* __restrict__ W,
    const float* __restrict__ Mg, const float* __restrict__ gbias,
    const float* __restrict__ pos, const float* __restrict__ lng,
    const float* __restrict__ lnb, const float* __restrict__ projb,
    const float* __restrict__ ws, const ushort* __restrict__ wq,
    const ushort* __restrict__ wp, float* __restrict__ out) {
    __shared__ __align__(16) char S[74560];
    char* xnC = S;
    char* qoC = S + 17408;
    char* kC = S + 34816;
    char* vC = S + 52224;
    char* pC = S + 69632;
    float* As = (float*)kC;
    float* xs = As + 289;
    float* red = xs + 34;
    float* stats = red + 136;
    float* muv = stats + 34;
    float* rsv = muv + 17;

    const int t = threadIdx.x;
    const int b = blockIdx.x;
    const int lane = t & 63, w = t >> 6;
    const int l15 = lane & 15, g = lane >> 4;
    const int aswz0 = (l15 & 7) << 4;

    for (int i = lane; i < 77; i += 64)
        ((i32x4*)(pC + w * 1232))[i] = (i32x4){0, 0, 0, 0};
    for (int i = t; i < 289; i += 256) As[i] = ws[i];
    if (t < 34) xs[t] = x[b * 34 + t];

    float W00[2], W01[2], W10[2], W11[2], gb2[2], bsc[2], bsh[2], lg[2], lb[2], pb[2];
#pragma unroll
    for (int j = 0; j < 2; j++) {
        int c = t + j * 256;
        W00[j] = W[c]; W01[j] = W[512 + c]; W10[j] = W[1024 + c]; W11[j] = W[1536 + c];
        gb2[j] = gbias[c]; bsc[j] = ws[1536 + c]; bsh[j] = ws[2048 + c];
        lg[j] = lng[c]; lb[j] = lnb[c]; pb[j] = projb[c];
    }
    __syncthreads();

    float xp[17][2];
    {
        float u_[17][2], dg_[17][2];
#pragma unroll
        for (int m = 0; m < 17; m++) {
            float x0 = xs[2 * m], x1 = xs[2 * m + 1];
#pragma unroll
            for (int j = 0; j < 2; j++) {
                float Mv = Mg[m * 512 + t + j * 256];
                u_[m][j] = Mv * (x0 * W10[j] + x1 * W11[j]);
                dg_[m][j] = Mv * (x0 * W00[j] + x1 * W01[j]);
            }
        }
#pragma unroll
        for (int n = 0; n < 17; n++) {
            float S0 = gb2[0], S1 = gb2[1];
#pragma unroll
            for (int m = 0; m < 17; m++) {
                float a = As[n * 17 + m];
                S0 += a * u_[m][0];
                S1 += a * u_[m][1];
            }
            float ad = As[n * 17 + n];
            float ov0 = S0 + ad * (dg_[n][0] - u_[n][0]);
            float ov1 = S1 + ad * (dg_[n][1] - u_[n][1]);
            xp[n][0] = fmaxf(ov0 * bsc[0] + bsh[0], 0.f) + pos[n * 512 + t];
            xp[n][1] = fmaxf(ov1 * bsc[1] + bsh[1], 0.f) + pos[n * 512 + t + 256];
        }
    }
#pragma unroll
    for (int n = 0; n < 17; n++) {
        float a = xp[n][0] + xp[n][1];
        float q2 = xp[n][0] * xp[n][0] + xp[n][1] * xp[n][1];
#pragma unroll
        for (int off = 32; off; off >>= 1) {
            a += __shfl_xor(a, off);
            q2 += __shfl_xor(q2, off);
        }
        if (lane == 0) { red[w * 34 + n] = a; red[w * 34 + 17 + n] = q2; }
    }
    __syncthreads();
    if (t < 34) stats[t] = red[t] + red[34 + t] + red[68 + t] + red[102 + t];
    __syncthreads();
    if (t < 17) {
        float mu = stats[t] * (1.f / 512.f);
        float var = stats[17 + t] * (1.f / 512.f) - mu * mu;
        muv[t] = mu;
        rsv[t] = 1.f / sqrtf(var + EPSq);
    }
    __syncthreads();
    {
        ushort* xnU = (ushort*)xnC;
#pragma unroll
        for (int n = 0; n < 17; n++) {
            int sw = (n & 7) << 4;
#pragma unroll
            for (int j = 0; j < 2; j++) {
                int c = t + j * 256;
                float xnv = (xp[n][j] - muv[n]) * rsv[n] * lg[j] + lb[j];
                xnU[(n * 1024 + ((2 * c) ^ sw)) >> 1] = f2bf(xnv);
            }
        }
    }
    __syncthreads();
    {
        const char* a0b = xnC + l15 * 1024;
        const char* a1b = xnC + 16 * 1024;
        for (int c = 0; c < 4; c++) {
            int tbase = w * 24 + c * 6;
            f32x4 acc0[6], acc1[6];
#pragma unroll
            for (int j = 0; j < 6; j++) {
                acc0[j] = (f32x4){0.f, 0.f, 0.f, 0.f};
                acc1[j] = (f32x4){0.f, 0.f, 0.f, 0.f};
            }
            const ushort* bp[6];
#pragma unroll
            for (int j = 0; j < 6; j++)
                bp[j] = wq + (size_t)((tbase + j) * 16 + l15) * 512 + g * 8;
#pragma unroll 4
            for (int ks = 0; ks < 16; ks++) {
                int colb = ks * 64 + g * 16;
                bf16x8 a0 = *(const bf16x8*)(a0b + (colb ^ aswz0));
                bf16x8 a1 = *(const bf16x8*)(a1b + colb);
#pragma unroll
                for (int j = 0; j < 6; j++) {
                    bf16x8 bv = *(const bf16x8*)(bp[j] + ks * 32);
                    acc0[j] = mfma16(a0, bv, acc0[j]);
                    acc1[j] = mfma16(a1, bv, acc1[j]);
                }
            }
#pragma unroll
            for (int j = 0; j < 6; j++) {
                int t_ = tbase + j;
                int which = t_ >> 5;
                int col = (t_ & 31) * 16 + l15;
                char* dst = which == 0 ? qoC : (which == 1 ? kC : vC);
#pragma unroll
                for (int r = 0; r < 4; r++) {
                    int n = g * 4 + r;
                    *(ushort*)(dst + n * 1024 + ((2 * col) ^ ((n & 7) << 4))) = f2bf(acc0[j][r]);
                }
                if (g == 0)
                    *(ushort*)(dst + 16 * 1024 + 2 * col) = f2bf(acc1[j][0]);
            }
        }
    }
    __syncthreads();
    ushort* pw16 = (ushort*)(pC + w * 1232);
#pragma unroll
    for (int hh = 0; hh < 2; hh++) {
        int hb = (2 * w + hh) * 128;
        f32x4 sa[2][2];
        sa[0][0] = (f32x4){0.f, 0.f, 0.f, 0.f}; sa[0][1] = sa[0][0];
        sa[1][0] = sa[0][0]; sa[1][1] = sa[0][0];
#pragma unroll
        for (int ks2 = 0; ks2 < 2; ks2++) {
            int cb = hb + ks2 * 64 + g * 16;
            bf16x8 qa0 = *(const bf16x8*)(qoC + l15 * 1024 + (cb ^ aswz0));
            bf16x8 qa1 = *(const bf16x8*)(qoC + 16 * 1024 + cb);
            bf16x8 kb0 = *(const bf16x8*)(kC + l15 * 1024 + (cb ^ aswz0));
            bf16x8 kb1 = *(const bf16x8*)(kC + 16 * 1024 + cb);
            sa[0][0] = mfma16(qa0, kb0, sa[0][0]);
            sa[1][0] = mfma16(qa1, kb0, sa[1][0]);
            sa[0][1] = mfma16(qa0, kb1, sa[0][1]);
            sa[1][1] = mfma16(qa1, kb1, sa[1][1]);
        }
#pragma unroll
        for (int mt = 0; mt < 2; mt++)
#pragma unroll
            for (int r = 0; r < 4; r++) {
                float sc0 = sa[mt][0][r];
                float sc1v = sa[mt][1][r];
                float sc1 = (l15 == 0) ? sc1v : -1e30f;
                float mx = fmaxf(sc0, sc1);
#pragma unroll
                for (int off = 1; off < 16; off <<= 1) mx = fmaxf(mx, __shfl_xor(mx, off));
                float e0 = __expf(sc0 - mx);
                float e1 = (l15 == 0) ? __expf(sc1v - mx) : 0.f;
                float sm = e0 + e1;
#pragma unroll
                for (int off = 1; off < 16; off <<= 1) sm += __shfl_xor(sm, off);
                float ri = 1.f / sm;
                int n = mt * 16 + g * 4 + r;
                if (n < 17) {
                    pw16[hh * 306 + n * 18 + l15] = f2bf(e0 * ri);
                    if (l15 == 0) pw16[hh * 306 + n * 18 + 16] = f2bf(e1 * ri);
                }
            }
    }
    __syncthreads();
#pragma unroll
    for (int hh = 0; hh < 2; hh++) {
        int hb = (2 * w + hh) * 128;
        float vv[18];
        vv[17] = 0.f;
#pragma unroll
        for (int m = 0; m < 17; m++)
            vv[m] = bfs(*(const ushort*)(vC + m * 1024 + ((hb + 2 * lane) ^ ((m & 7) << 4))));
        const uint* pr = (const uint*)(pC + w * 1232 + hh * 612);
#pragma unroll
        for (int n = 0; n < 17; n++) {
            float o_ = 0.f;
#pragma unroll
            for (int q = 0; q < 9; q++) {
                uint p2 = pr[n * 9 + q];
                o_ += bflo(p2) * vv[2 * q] + bfhi(p2) * vv[2 * q + 1];
            }
            *(ushort*)(qoC + n * 1024 + ((hb + 2 * lane) ^ ((n & 7) << 4))) = f2bf(o_);
        }
    }
    __syncthreads();
    {
        f32x4 pa0[8], pa1[8];
#pragma unroll
        for (int nt = 0; nt < 8; nt++) {
            pa0[nt] = (f32x4){0.f, 0.f, 0.f, 0.f};
            pa1[nt] = (f32x4){0.f, 0.f, 0.f, 0.f};
        }
        const ushort* wpB[8];
#pragma unroll
        for (int nt = 0; nt < 8; nt++)
            wpB[nt] = wp + (size_t)(w * 128 + nt * 16 + l15) * 512 + g * 8;
#pragma unroll 4
        for (int ks = 0; ks < 16; ks++) {
            int colb = ks * 64 + g * 16;
            bf16x8 a0 = *(const bf16x8*)(qoC + l15 * 1024 + (colb ^ aswz0));
            bf16x8 a1 = *(const bf16x8*)(qoC + 16 * 1024 + colb);
#pragma unroll
            for (int nt = 0; nt < 8; nt++) {
                bf16x8 bv = *(const bf16x8*)(wpB[nt] + ks * 32);
                pa0[nt] = mfma16(a0, bv, pa0[nt]);
                pa1[nt] = mfma16(a1, bv, pa1[nt]);
            }
        }
        float* pAcc = (float*)kC;
#pragma unroll
        for (int nt = 0; nt < 8; nt++) {
            int col = w * 128 + nt * 16 + l15;
#pragma unroll
            for (int r = 0; r < 4; r++) {
                int n = g * 4 + r;
                pAcc[n * 512 + col] = pa0[nt][r];
            }
            if (g == 0) pAcc[16 * 512 + col] = pa1[nt][0];
        }
    }
    __syncthreads();
    {
        const float* pAcc = (const float*)kC;
#pragma unroll
        for (int n = 0; n < 17; n++) {
            size_t o0 = ((size_t)b * 17 + n) * 512;
            out[o0 + t] = xp[n][0] + pAcc[n * 512 + t] + pb[0];
            out[o0 + t + 256] = xp[n][1] + pAcc[n * 512 + t + 256] + pb[1];
        }
    }
}

extern "C" void kernel_launch(void* const* d_in, const int* in_sizes, int n_in,
                              void* d_out, int out_size, void* d_ws, size_t ws_size,
                              hipStream_t stream) {
    const float* x = (const float*)d_in[0];
    const float* adj = (const float*)d_in[1];
    const float* adj2 = (const float*)d_in[2];
    const float* W = (const float*)d_in[3];
    const float* Mg = (const float*)d_in[4];
    const float* gbias = (const float*)d_in[5];
    const float* bng = (const float*)d_in[6];
    const float* bnb = (const float*)d_in[7];
    const float* pos = (const float*)d_in[8];
    const float* lng = (const float*)d_in[9];
    const float* lnb = (const float*)d_in[10];
    const float* qkvw = (const float*)d_in[11];
    const float* projw = (const float*)d_in[12];
    const float* projb = (const float*)d_in[13];
    float* ws = (float*)d_ws;
    float* out = (float*)d_out;
    ushort* wq = (ushort*)((char*)d_ws + 16384);
    ushort* wp = (ushort*)((char*)d_ws + 1589248);

    k_prep<<<1, 512, 0, stream>>>(adj, adj2, ws);
    k_stats<<<256, 512, 0, stream>>>(x, W, Mg, gbias, ws);
    k_finalize<<<1, 512, 0, stream>>>(bng, bnb, ws);
    k_wconv<<<3072, 256, 0, stream>>>(qkvw, projw, wq, wp);

    const size_t base = 2113536ULL;
    const size_t xnBytes = 71303168ULL;  // 69632*512*2
    int P = 0;
    for (int c = 1; c <= 8; c <<= 1) {
        size_t need = base + xnBytes + (size_t)(69632 / c) * 1536 * 2;
        if (need <= ws_size) { P = c; break; }
    }
    if (P) {
        ushort* xn = (ushort*)((char*)d_ws + base);       // also the o buffer
        ushort* qkvB = (ushort*)((char*)d_ws + base + xnBytes);
        k_pre<<<4096, 256, 0, stream>>>(x, W, Mg, gbias, pos, lng, lnb, ws, xn, out);
        int spp = 4096 / P;
        int rpp = spp * 17;
        for (int p = 0; p < P; p++) {
            const ushort* xnp = xn + (size_t)p * rpp * 512;
            dim3 gq(rpp / 128, 12);
            k_qkv<<<gq, 256, 0, stream>>>(xnp, wq, qkvB);
            k_attn<<<spp * 2, 256, 0, stream>>>(qkvB, xn, p * spp);
        }
        dim3 gp(544, 4);
        k_proj<<<gp, 256, 0, stream>>>(xn, wp, projb, out);
    } else {
        k_fused<<<Bq, 256, 0, stream>>>(x, W, Mg, gbias, pos, lng, lnb, projb,
                                        ws, wq, wp, out);
    }
}